// Round 1
// baseline (3667.875 us; speedup 1.0000x reference)
//
#include <hip/hip_runtime.h>
#include <hip/hip_bf16.h>
#include <math.h>

typedef __attribute__((ext_vector_type(8))) short bf16x8;
typedef __attribute__((ext_vector_type(4))) float f32x4;

constexpr int NPTS = 65536;
constexpr int ENC  = 512;
constexpr int P    = 4096;
constexpr int JD   = 1024;   // 2*ENC
constexpr int ID   = 8192;   // 2*P
constexpr int CH   = 8192;   // point chunk
constexpr int NCH  = NPTS / CH;
constexpr int LDK  = 8192;   // k-stride (elements) of all GEMM operand rows

constexpr float INV_R   = 20.0f;                  // 1/0.05
constexpr float INV2PI  = 0.15915494309189535f;
constexpr float SQRT_D  = 22.627416997969522f;    // sqrt(512)

__device__ __forceinline__ unsigned short f2bf(float f) {
    unsigned int u = __float_as_uint(f);
    u = (u + 0x7FFFu + ((u >> 16) & 1u)) >> 16;
    return (unsigned short)u;
}

// phases are up to ~±350 revolutions: must fract-reduce before v_sin/v_cos
__device__ __forceinline__ void sincos_rev(float p, float* s, float* c) {
    float r = p * INV2PI;
    r = r - floorf(r);                 // [0,1)
    *s = __builtin_amdgcn_sinf(r);     // sin(2*pi*r)
    *c = __builtin_amdgcn_cosf(r);
}

__device__ __forceinline__ void gload16(const void* g, void* l) {
    __builtin_amdgcn_global_load_lds(
        (const __attribute__((address_space(1))) unsigned int*)g,
        (__attribute__((address_space(3))) unsigned int*)l, 16, 0, 0);
}

// ---------------- gen transposed e-matrices (phase A) ----------------
// eAT [1024][CH], eBT [8192][CH]; each thread: one row r, two consecutive points
__global__ __launch_bounds__(256)
void gen_t(const float* __restrict__ pts, const float* __restrict__ A,
           const float* __restrict__ B, unsigned short* __restrict__ eAT,
           unsigned short* __restrict__ eBT, int n0) {
    int idx = blockIdx.x * 256 + threadIdx.x;
    int nh  = idx & (CH / 2 - 1);      // 4096 pairs
    int r   = idx >> 12;               // row in [0, 4608): first 512 = A rows
    int nl  = nh * 2;
    int n   = n0 + nl;
    float x0a = pts[n * 3 + 0], x1a = pts[n * 3 + 1], x2a = pts[n * 3 + 2];
    float x0b = pts[n * 3 + 3], x1b = pts[n * 3 + 4], x2b = pts[n * 3 + 5];
    float w0, w1, w2;
    unsigned short *dc, *dsn;
    if (r < ENC) {
        w0 = A[r]; w1 = A[ENC + r]; w2 = A[2 * ENC + r];
        dc  = eAT + (size_t)r * CH + nl;
        dsn = eAT + (size_t)(r + ENC) * CH + nl;
    } else {
        int i = r - ENC;
        w0 = B[i]; w1 = B[P + i]; w2 = B[2 * P + i];
        dc  = eBT + (size_t)i * CH + nl;
        dsn = eBT + (size_t)(i + P) * CH + nl;
    }
    float pa = (x0a * w0 + x1a * w1 + x2a * w2) * INV_R;
    float pb = (x0b * w0 + x1b * w1 + x2b * w2) * INV_R;
    float sa, ca, sb, cb;
    sincos_rev(pa, &sa, &ca);
    sincos_rev(pb, &sb, &cb);
    ushort2 vc; vc.x = f2bf(ca); vc.y = f2bf(cb);
    ushort2 vs; vs.x = f2bf(sa); vs.y = f2bf(sb);
    *(ushort2*)dc  = vc;
    *(ushort2*)dsn = vs;
}

// ---------------- gen eB row-major (phase C) ----------------
// eB [CH][8192]; thread: one point, two consecutive i
__global__ __launch_bounds__(256)
void gen_b(const float* __restrict__ pts, const float* __restrict__ B,
           unsigned short* __restrict__ eB, int n0) {
    int idx = blockIdx.x * 256 + threadIdx.x;
    int ih = idx & 2047;
    int ln = idx >> 11;
    int i  = ih * 2;
    int n  = n0 + ln;
    float x0 = pts[n * 3 + 0], x1 = pts[n * 3 + 1], x2 = pts[n * 3 + 2];
    float p0 = (x0 * B[i]     + x1 * B[P + i]     + x2 * B[2 * P + i])     * INV_R;
    float p1 = (x0 * B[i + 1] + x1 * B[P + i + 1] + x2 * B[2 * P + i + 1]) * INV_R;
    float s0, c0, s1, c1;
    sincos_rev(p0, &s0, &c0);
    sincos_rev(p1, &s1, &c1);
    ushort2 vc; vc.x = f2bf(c0); vc.y = f2bf(c1);
    ushort2 vs; vs.x = f2bf(s0); vs.y = f2bf(s1);
    *(ushort2*)(eB + (size_t)ln * ID + i)     = vc;
    *(ushort2*)(eB + (size_t)ln * ID + P + i) = vs;
}

// ---------------- GEMM: C[m][n] (+)= sum_k Ag[m][k]*Bg[n][k] ----------------
// Ag [Mrows][8192] bf16, Bg [Ncols][8192] bf16, 128x128 tile, BK=64,
// 4 waves x (64x64), XOR-swizzled LDS, global_load_lds x16B staging.
template <bool ACCUM>
__global__ __launch_bounds__(256)
void gemm_nt(const unsigned short* __restrict__ Ag,
             const unsigned short* __restrict__ Bg,
             float* __restrict__ C, int ldc, int K, int beta) {
    __shared__ unsigned short lds[2 * 128 * 64];   // 32 KiB
    unsigned short* ldsA = lds;
    unsigned short* ldsB = lds + 128 * 64;

    const int tid  = threadIdx.x;
    const int wave = tid >> 6, lane = tid & 63;
    const int l8 = lane >> 3, s8 = lane & 7;
    const int m0 = blockIdx.x * 128, n0 = blockIdx.y * 128;
    const int mr = lane & 15, q = lane >> 4;
    const int wm = (wave & 1) * 64, wn = (wave >> 1) * 64;

    const char* aG = (const char*)Ag;
    const char* bG = (const char*)Bg;
    size_t aoff[4], boff[4];
#pragma unroll
    for (int t = 0; t < 4; ++t) {
        int rowA = m0 + (wave * 4 + t) * 8 + l8;
        int rowB = n0 + (wave * 4 + t) * 8 + l8;
        size_t co = (size_t)(s8 ^ l8) * 16;        // swizzled 16B slot in 128B row
        aoff[t] = (size_t)rowA * (LDK * 2) + co;
        boff[t] = (size_t)rowB * (LDK * 2) + co;
    }

    f32x4 acc[4][4];
#pragma unroll
    for (int a = 0; a < 4; ++a)
#pragma unroll
        for (int b = 0; b < 4; ++b) acc[a][b] = (f32x4){0.f, 0.f, 0.f, 0.f};

    for (int kb = 0; kb < K; kb += 64) {
        __syncthreads();
#pragma unroll
        for (int t = 0; t < 4; ++t) {
            gload16(aG + aoff[t] + (size_t)kb * 2, ldsA + (wave * 4 + t) * 512);
            gload16(bG + boff[t] + (size_t)kb * 2, ldsB + (wave * 4 + t) * 512);
        }
        __syncthreads();
#pragma unroll
        for (int kk = 0; kk < 2; ++kk) {
            bf16x8 af[4], bfr[4];
#pragma unroll
            for (int mi = 0; mi < 4; ++mi) {
                int m = wm + mi * 16 + mr;
                af[mi] = *(const bf16x8*)(ldsA + m * 64 + (((kk * 4 + q) ^ (m & 7)) * 8));
            }
#pragma unroll
            for (int ni = 0; ni < 4; ++ni) {
                int n = wn + ni * 16 + mr;
                bfr[ni] = *(const bf16x8*)(ldsB + n * 64 + (((kk * 4 + q) ^ (n & 7)) * 8));
            }
#pragma unroll
            for (int mi = 0; mi < 4; ++mi)
#pragma unroll
                for (int ni = 0; ni < 4; ++ni)
                    acc[mi][ni] = __builtin_amdgcn_mfma_f32_16x16x32_bf16(
                        af[mi], bfr[ni], acc[mi][ni], 0, 0, 0);
        }
    }

    // C/D layout: col = lane&15, row = (lane>>4)*4 + reg
#pragma unroll
    for (int mi = 0; mi < 4; ++mi)
#pragma unroll
        for (int ni = 0; ni < 4; ++ni)
#pragma unroll
            for (int r = 0; r < 4; ++r) {
                int m = m0 + wm + mi * 16 + q * 4 + r;
                int n = n0 + wn + ni * 16 + mr;
                size_t off = (size_t)m * ldc + n;
                float v = acc[mi][ni][r];
                if (ACCUM) { if (beta) v += C[off]; }
                C[off] = v;
            }
}

// ---------------- MT fp32 -> bf16 ----------------
__global__ __launch_bounds__(256)
void cvt(const float* __restrict__ src, unsigned short* __restrict__ dst) {
    int idx = blockIdx.x * 256 + threadIdx.x;
    float4 v = ((const float4*)src)[idx];
    ushort4 o;
    o.x = f2bf(v.x); o.y = f2bf(v.y); o.z = f2bf(v.z); o.w = f2bf(v.w);
    ((ushort4*)dst)[idx] = o;
}

// ---------------- epilogue: re/im, row norm, scale (in place on d_out) ----
__global__ __launch_bounds__(256)
void epi(float* __restrict__ out, const float* __restrict__ pts,
         const float* __restrict__ A) {
    int n = blockIdx.x;
    int t = threadIdx.x;
    float x0 = pts[n * 3 + 0], x1 = pts[n * 3 + 1], x2 = pts[n * 3 + 2];
    float* row = out + (size_t)n * JD;
    float reA[2], imA[2];
    float ssum = 0.f;
#pragma unroll
    for (int u = 0; u < 2; ++u) {
        int j = t + u * 256;
        float pa = (x0 * A[j] + x1 * A[ENC + j] + x2 * A[2 * ENC + j]) * INV_R;
        float s, c;
        sincos_rev(pa, &s, &c);
        float gc = row[j], gs = row[ENC + j];
        float re = gc * c + gs * s;
        float im = gs * c - gc * s;
        reA[u] = re; imA[u] = im;
        ssum += re * re + im * im;
    }
#pragma unroll
    for (int off = 32; off > 0; off >>= 1) ssum += __shfl_down(ssum, off);
    __shared__ float red[4];
    if ((t & 63) == 0) red[t >> 6] = ssum;
    __syncthreads();
    float tot = red[0] + red[1] + red[2] + red[3];
    float scale = SQRT_D / sqrtf(tot);
#pragma unroll
    for (int u = 0; u < 2; ++u) {
        int j = t + u * 256;
        row[j]       = reA[u] * scale;
        row[ENC + j] = imA[u] * scale;
    }
}

extern "C" void kernel_launch(void* const* d_in, const int* in_sizes, int n_in,
                              void* d_out, int out_size, void* d_ws, size_t ws_size,
                              hipStream_t stream) {
    const float* pts = (const float*)d_in[0];
    const float* A   = (const float*)d_in[1];
    const float* B   = (const float*)d_in[2];
    float* out = (float*)d_out;
    char* ws = (char*)d_ws;

    // ws layout (192 MiB total):
    //   [0, 16M)          eAT  [1024][8192] bf16   (phase A)  / eB [8192][8192] (phase C, spans both)
    //   [16M, 151M)       eBT  [8192][8192] bf16   (phase A)
    //   [151M, 183M)      MTf  [1024][8192] fp32
    //   [183M, 199M)      MTb  [1024][8192] bf16
    unsigned short* eAT = (unsigned short*)ws;
    unsigned short* eBT = (unsigned short*)(ws + (size_t)JD * CH * 2);
    unsigned short* eBw = (unsigned short*)ws;
    size_t offMT = (size_t)(JD + ID) * CH * 2;
    float* MTf = (float*)(ws + offMT);
    unsigned short* MTb = (unsigned short*)(ws + offMT + (size_t)JD * ID * 4);

    for (int c = 0; c < NCH; ++c) {
        gen_t<<<dim3(73728), 256, 0, stream>>>(pts, A, B, eAT, eBT, c * CH);
        // MT[j][i] += eAT[j][:] . eBT[i][:]
        gemm_nt<true><<<dim3(JD / 128, ID / 128), 256, 0, stream>>>(
            eAT, eBT, MTf, ID, CH, c);
    }
    cvt<<<dim3(8192), 256, 0, stream>>>(MTf, MTb);
    for (int c = 0; c < NCH; ++c) {
        gen_b<<<dim3(65536), 256, 0, stream>>>(pts, B, eBw, c * CH);
        // G[ln][j] = eB[ln][:] . MTb[j][:]  -> straight into d_out rows
        gemm_nt<false><<<dim3(CH / 128, JD / 128), 256, 0, stream>>>(
            eBw, MTb, out + (size_t)c * CH * JD, JD, ID, 0);
    }
    epi<<<dim3(NPTS), 256, 0, stream>>>(out, pts, A);
}